// Round 1
// baseline (619.421 us; speedup 1.0000x reference)
//
#include <hip/hip_runtime.h>
#include <hip/hip_bf16.h>
#include <hip/hip_cooperative_groups.h>
#include <cmath>

namespace cg = cooperative_groups;

#define NODES 150000
#define DIM 64
#define EDGES 1200000
#define NREL 32
#define NLAYERS 2
#define NND (NODES*DIM)
#define SCAN_NB ((NODES + 255)/256)   // 586
#define RBLK (NODES/16)               // 9375 row-blocks of 16 (gemm)
#define NRB4 (NODES/4)                // 37500 row-quads (agg)

typedef __hip_bfloat16 bf16;
typedef unsigned short ushort16;
typedef __attribute__((ext_vector_type(8))) short bf16x8;  // MFMA A/B frag (4 VGPRs)
typedef __attribute__((ext_vector_type(4))) float f32x4;   // MFMA C/D frag

__device__ __forceinline__ float b2f(bf16 v){ return __bfloat162float(v); }
__device__ __forceinline__ short f2bs(float f){
  bf16 h = __float2bfloat16(f);
  return *(short*)&h;
}

// sentinel: encode ws_size (MB) into output (tripwire only)
__global__ void __launch_bounds__(256) k_sentinel(float* __restrict__ out, float wsmb){
  int i = blockIdx.x*256 + threadIdx.x;
  if (i < NND) out[i] = wsmb;
}

// ---------------------------------------------------------------------------
// ONE cooperative kernel replacing: memset(count) + k_relboth + k_inithist +
// k_scan1 + k_scan2 + k_scan3 + k_build  (7 graph nodes -> 1).
// Phases separated by grid.sync(); per-block scan state held in regs/LDS
// across syncs (blocks stay resident under cooperative launch).
// Grid MUST be SCAN_NB blocks x 256 (one block per 256-node scan chunk);
// 586 blocks co-resident trivially (<< 2048 cap).
// ---------------------------------------------------------------------------
__global__ void __launch_bounds__(256) k_csr(const float* __restrict__ Wr,
                                             const float* __restrict__ a,
                                             const float* __restrict__ rel,
                                             float* __restrict__ s_rel,
                                             const int* __restrict__ src,
                                             const int* __restrict__ dst,
                                             const int* __restrict__ et,
                                             int* __restrict__ count,
                                             int* __restrict__ bsum,
                                             int* __restrict__ row_ptr,
                                             ushort16* __restrict__ pl,
                                             unsigned* __restrict__ cse){
  cg::grid_group grid = cg::this_grid();
  int tid = threadIdx.x;
  int gtid = blockIdx.x*256 + tid;
  int gstride = gridDim.x*256;   // 150016

  // ---- phase 0: zero count; blocks 0,1 also compute s_rel (both layers) ----
  for (int i = gtid; i < NODES; i += gstride) count[i] = 0;
  if (blockIdx.x < 2){
    int l = blockIdx.x;
    const float* Wr_l  = Wr  + l*DIM*DIM;
    const float* a_l   = a   + l*3*DIM;
    const float* rel_l = rel + l*NREL*DIM;
    __shared__ float wsh[DIM];
    if (tid < DIM){
      float s = 0.f;
      for (int j = 0; j < DIM; j++) s += Wr_l[tid*DIM + j] * a_l[DIM + j];
      wsh[tid] = s;
    }
    __syncthreads();
    if (tid < NREL){
      float r = 0.f;
      for (int k = 0; k < DIM; k++) r += rel_l[tid*DIM + k] * wsh[k];
      s_rel[l*NREL + tid] = r;
    }
  }
  grid.sync();

  // ---- phase 1: histogram; pl[e] = local slot (atomic return) ----
  for (int e = gtid; e < EDGES; e += gstride)
    pl[e] = (ushort16)atomicAdd(&count[dst[e]], 1);
  grid.sync();

  // ---- phase 2: per-block exclusive scan of this block's 256 counts ----
  __shared__ int s[256];
  int i = blockIdx.x*256 + tid;
  int c = (i < NODES) ? count[i] : 0;
  s[tid] = c;
  __syncthreads();
  #pragma unroll
  for (int off = 1; off < 256; off <<= 1){
    int t = (tid >= off) ? s[tid - off] : 0;
    __syncthreads();
    s[tid] += t;
    __syncthreads();
  }
  int lexcl = s[tid] - c;                 // kept in a register across syncs
  if (tid == 255) bsum[blockIdx.x] = s[255];
  grid.sync();

  // ---- phase 3: block 0 scans the SCAN_NB block sums (3 per thread) ----
  if (blockIdx.x == 0){
    __shared__ int sb[256];
    int b0 = tid*3;
    int v0 = (b0   < SCAN_NB) ? bsum[b0]   : 0;
    int v1 = (b0+1 < SCAN_NB) ? bsum[b0+1] : 0;
    int v2 = (b0+2 < SCAN_NB) ? bsum[b0+2] : 0;
    int tsum = v0 + v1 + v2;
    sb[tid] = tsum;
    __syncthreads();
    #pragma unroll
    for (int off = 1; off < 256; off <<= 1){
      int t = (tid >= off) ? sb[tid - off] : 0;
      __syncthreads();
      sb[tid] += t;
      __syncthreads();
    }
    int pfx = sb[tid] - tsum;             // exclusive prefix of this thread's 3
    if (b0   < SCAN_NB) bsum[b0]   = pfx;
    if (b0+1 < SCAN_NB) bsum[b0+1] = pfx + v0;
    if (b0+2 < SCAN_NB) bsum[b0+2] = pfx + v0 + v1;
  }
  grid.sync();

  // ---- phase 4: row_ptr = local excl + scanned block base ----
  if (i < NODES) row_ptr[i] = lexcl + bsum[blockIdx.x];
  if (gtid == 0) row_ptr[NODES] = EDGES;
  grid.sync();

  // ---- phase 5: atomic-free scatter build of packed CSR ----
  for (int e = gtid; e < EDGES; e += gstride){
    int p = row_ptr[dst[e]] + (int)pl[e];
    cse[p] = (unsigned)src[e] | ((unsigned)et[e] << 18);
  }
}

__device__ __forceinline__ bf16x8 pack8(float4 lo, float4 hi){
  bf16x8 r;
  ((short*)&r)[0] = f2bs(lo.x); ((short*)&r)[1] = f2bs(lo.y);
  ((short*)&r)[2] = f2bs(lo.z); ((short*)&r)[3] = f2bs(lo.w);
  ((short*)&r)[4] = f2bs(hi.x); ((short*)&r)[5] = f2bs(hi.y);
  ((short*)&r)[6] = f2bs(hi.z); ((short*)&r)[7] = f2bs(hi.w);
  return r;
}

// per layer, MFMA: xt = x @ W. F32IN=true reads f32 rows (layer 0: node_emb
// directly, converting inline with the same __float2bfloat16 rounding the old
// conversion pass used -> bit-identical). s_src/s_dst from accumulators.
template<bool F32IN>
__global__ void __launch_bounds__(256) k_gemm_t(const void* __restrict__ xin_,
                                                bf16* __restrict__ xt,
                                                const float* __restrict__ W_l,
                                                const float* __restrict__ a_l,
                                                float* __restrict__ s_src_a,
                                                float* __restrict__ s_dst_a){
  __shared__ float Ws[DIM*DIM];   // 16 KB staged f32 W
  int tid = threadIdx.x;
  for (int i = tid; i < DIM*DIM; i += 256) Ws[i] = W_l[i];
  __syncthreads();

  int lane = tid & 63;
  int l15  = lane & 15;
  int quad = lane >> 4;

  bf16x8 bfrag[4][2];
  #pragma unroll
  for (int nt = 0; nt < 4; nt++)
    #pragma unroll
    for (int kh = 0; kh < 2; kh++)
      #pragma unroll
      for (int j = 0; j < 8; j++){
        int k = kh*32 + quad*8 + j;
        ((short*)&bfrag[nt][kh])[j] = f2bs(Ws[k*DIM + nt*16 + l15]);
      }

  float asrc[4], adst[4];
  #pragma unroll
  for (int nt = 0; nt < 4; nt++){
    asrc[nt] = a_l[nt*16 + l15];
    adst[nt] = a_l[2*DIM + nt*16 + l15];
  }

  int gw = blockIdx.x*4 + (tid >> 6);
  int nw = gridDim.x*4;
  for (int rb = gw; rb < RBLK; rb += nw){
    int r0 = rb*16;
    const size_t abase = (size_t)(r0 + l15)*DIM + quad*8;
    bf16x8 a0, a1;
    if constexpr (F32IN){
      const float* xf = (const float*)xin_ + abase;
      float4 f0 = *(const float4*)(xf);
      float4 f1 = *(const float4*)(xf + 4);
      float4 f2 = *(const float4*)(xf + 32);
      float4 f3 = *(const float4*)(xf + 36);
      a0 = pack8(f0, f1);
      a1 = pack8(f2, f3);
    } else {
      const bf16* xb = (const bf16*)xin_;
      a0 = *(const bf16x8*)(xb + abase);
      a1 = *(const bf16x8*)(xb + abase + 32);
    }

    f32x4 acc[4];
    #pragma unroll
    for (int nt = 0; nt < 4; nt++){
      acc[nt] = (f32x4){0.f, 0.f, 0.f, 0.f};
      acc[nt] = __builtin_amdgcn_mfma_f32_16x16x32_bf16(a0, bfrag[nt][0], acc[nt], 0, 0, 0);
      acc[nt] = __builtin_amdgcn_mfma_f32_16x16x32_bf16(a1, bfrag[nt][1], acc[nt], 0, 0, 0);
    }

    float p[4], q[4];
    #pragma unroll
    for (int i = 0; i < 4; i++){
      p[i] = acc[0][i]*asrc[0] + acc[1][i]*asrc[1] + acc[2][i]*asrc[2] + acc[3][i]*asrc[3];
      q[i] = acc[0][i]*adst[0] + acc[1][i]*adst[1] + acc[2][i]*adst[2] + acc[3][i]*adst[3];
      #pragma unroll
      for (int off = 8; off > 0; off >>= 1){
        p[i] += __shfl_xor(p[i], off, 64);
        q[i] += __shfl_xor(q[i], off, 64);
      }
    }
    if (l15 < 4){
      float pv = (l15 == 0) ? p[0] : (l15 == 1) ? p[1] : (l15 == 2) ? p[2] : p[3];
      float qv = (l15 == 0) ? q[0] : (l15 == 1) ? q[1] : (l15 == 2) ? q[2] : q[3];
      int r = r0 + quad*4 + l15;
      s_src_a[r] = pv;
      s_dst_a[r] = qv;
    }

    #pragma unroll
    for (int nt = 0; nt < 4; nt++)
      #pragma unroll
      for (int i = 0; i < 4; i++)
        xt[(size_t)(r0 + quad*4 + i)*DIM + nt*16 + l15] = __float2bfloat16(acc[nt][i]);
  }
}

// per layer: FOUR rows per wave (16-lane groups). Lane l15 of group grp covers
// columns [l15*4, l15*4+4) of row rb*4+grp. Per edge: one 8 B load (4 bf16)
// feeds 4 fmas; 2 shfls serve the whole group. 4 independent row chains per
// wave + MLP=4 gathers per group = 16 loads in flight per wave.
// Guard-free: idle scoring lanes carry wl=0 -> weight-0 row-0 gathers.
// All shfl sources stay inside the lane's own (active) group, so inter-group
// trip-count divergence is safe.
// mode0: write xnext only. mode1: fused finale out=(node+x1+x2)/3, no xnext.
__global__ void __launch_bounds__(256) k_agg(const int* __restrict__ row_ptr,
                                             const unsigned* __restrict__ cse,
                                             const float* __restrict__ s_src_a,
                                             const float* __restrict__ s_dst_a,
                                             const float* __restrict__ s_rel,
                                             const bf16* __restrict__ xt,
                                             bf16* __restrict__ xnext,
                                             const float* __restrict__ node,
                                             const bf16* __restrict__ x1,
                                             float* __restrict__ out, int mode){
  int lane = threadIdx.x & 63;
  int grp  = lane >> 4;
  int l15  = lane & 15;
  int gw = blockIdx.x*4 + (threadIdx.x >> 6);
  int nw = gridDim.x*4;
  for (int rb = gw; rb < NRB4; rb += nw){
    int row = rb*4 + grp;
    int beg = row_ptr[row], end = row_ptr[row+1];
    float sdst = s_dst_a[row];
    float h0 = 0.f, h1 = 0.f, h2 = 0.f, h3 = 0.f;
    float wsuml = 0.f;
    for (int jb = beg; jb < end; jb += 16){
      int n = end - jb; if (n > 16) n = 16;
      unsigned pkv = 0u; float wl = 0.f;
      if (l15 < n){
        pkv = cse[jb + l15];
        int sl = (int)(pkv & 0x3FFFFu);
        int rl = (int)(pkv >> 18);
        float e = s_src_a[sl] + s_rel[rl] + sdst;
        e = e > 0.f ? e : 0.2f*e;
        wl = __expf(e);
      }
      wsuml += wl;
      int nk = (n + 3) & ~3;
      for (int j0 = 0; j0 < nk; j0 += 4){
        unsigned lo[4], hi[4];
        float wg[4];
        #pragma unroll
        for (int u = 0; u < 4; u++){
          int srcl = grp*16 + j0 + u;               // within this lane's group
          int s    = (int)(__shfl(pkv, srcl, 64) & 0x3FFFFu);
          wg[u]    = __shfl(wl, srcl, 64);
          uint2 d  = *(const uint2*)(xt + (size_t)s*DIM + l15*4);  // 4 bf16
          lo[u] = d.x; hi[u] = d.y;
        }
        #pragma unroll
        for (int u = 0; u < 4; u++){
          h0 = fmaf(wg[u], __uint_as_float(lo[u] << 16),          h0);
          h1 = fmaf(wg[u], __uint_as_float(lo[u] & 0xffff0000u),  h1);
          h2 = fmaf(wg[u], __uint_as_float(hi[u] << 16),          h2);
          h3 = fmaf(wg[u], __uint_as_float(hi[u] & 0xffff0000u),  h3);
        }
      }
    }
    // group-wide (16-lane) reductions: xor masks 1,2,4,8 stay inside the group
    float wsum = wsuml;
    #pragma unroll
    for (int off = 8; off > 0; off >>= 1) wsum += __shfl_xor(wsum, off, 64);

    float inv = 1.f / (wsum + 1e-10f);
    float v0 = h0*inv, v1 = h1*inv, v2 = h2*inv, v3 = h3*inv;
    v0 = v0 > 0.f ? v0 : expm1f(v0);
    v1 = v1 > 0.f ? v1 : expm1f(v1);
    v2 = v2 > 0.f ? v2 : expm1f(v2);
    v3 = v3 > 0.f ? v3 : expm1f(v3);
    float ss = v0*v0 + v1*v1 + v2*v2 + v3*v3;
    #pragma unroll
    for (int off = 8; off > 0; off >>= 1) ss += __shfl_xor(ss, off, 64);
    float rinv = 1.f / fmaxf(sqrtf(ss), 1e-12f);
    float x0 = v0*rinv, x1v = v1*rinv, x2 = v2*rinv, x3 = v3*rinv;

    size_t i = (size_t)row*DIM + l15*4;
    if (mode == 0){
      ushort16 st[4] = { (ushort16)((unsigned)f2bs(x0) & 0xffffu),
                         (ushort16)((unsigned)f2bs(x1v) & 0xffffu),
                         (ushort16)((unsigned)f2bs(x2) & 0xffffu),
                         (ushort16)((unsigned)f2bs(x3) & 0xffffu) };
      uint2 pk;
      pk.x = (unsigned)st[0] | ((unsigned)st[1] << 16);
      pk.y = (unsigned)st[2] | ((unsigned)st[3] << 16);
      *(uint2*)(xnext + i) = pk;
    } else {
      float4 nd = *(const float4*)(node + i);
      uint2 xo  = *(const uint2*)(x1 + i);
      float o0 = (nd.x + __uint_as_float(xo.x << 16)         + x0 ) * (1.f/3.f);
      float o1 = (nd.y + __uint_as_float(xo.x & 0xffff0000u) + x1v) * (1.f/3.f);
      float o2 = (nd.z + __uint_as_float(xo.y << 16)         + x2 ) * (1.f/3.f);
      float o3 = (nd.w + __uint_as_float(xo.y & 0xffff0000u) + x3 ) * (1.f/3.f);
      *(float4*)(out + i) = make_float4(o0, o1, o2, o3);
    }
  }
}

extern "C" void kernel_launch(void* const* d_in, const int* in_sizes, int n_in,
                              void* d_out, int out_size, void* d_ws, size_t ws_size,
                              hipStream_t stream){
  const float* node = (const float*)d_in[0];
  const float* W    = (const float*)d_in[1];
  const float* Wr   = (const float*)d_in[2];
  const float* a    = (const float*)d_in[3];
  const float* rel  = (const float*)d_in[4];
  const int*   ei   = (const int*)d_in[5];
  const int*   et   = (const int*)d_in[6];
  const int* src = ei;
  const int* dst = ei + EDGES;
  float* out = (float*)d_out;

  // ---- workspace layout (~47 MB; proven to fit) ----
  char* w = (char*)d_ws;
  size_t off = 0;
  bf16* B  = (bf16*)(w + off); off += (size_t)NND*2;             // 19.2 MB xt1, then xt2
  bf16* XN = (bf16*)(w + off); off += (size_t)NND*2;             // 19.2 MB x1
  unsigned* cse = (unsigned*)(w + off); off += (size_t)EDGES*4;  //  4.8 MB CSR packed
  ushort16* pl = (ushort16*)(w + off); off += (size_t)EDGES*2;   //  2.4 MB per-edge local slot
  int* row_ptr = (int*)(w + off); off += (size_t)(NODES+1)*4;    //  0.6 MB
  int* count   = (int*)(w + off); off += (size_t)NODES*4;        //  0.6 MB
  int* bsum    = (int*)(w + off); off += (size_t)SCAN_NB*4;      //  2.3 KB
  float* s_src = (float*)(w + off); off += (size_t)NODES*4;      //  0.6 MB
  float* s_dst = (float*)(w + off); off += (size_t)NODES*4;      //  0.6 MB
  float* s_rel = (float*)(w + off); off += 2*NREL*4;

  if (ws_size < off){
    k_sentinel<<<(NND + 255)/256, 256, 0, stream>>>(out, (float)ws_size * 1e-6f);
    return;
  }

  // one-time CSR build + s_rel, fully fused (cooperative; 7 nodes -> 1)
  {
    void* args[] = { (void*)&Wr, (void*)&a, (void*)&rel, (void*)&s_rel,
                     (void*)&src, (void*)&dst, (void*)&et,
                     (void*)&count, (void*)&bsum, (void*)&row_ptr,
                     (void*)&pl, (void*)&cse };
    hipLaunchCooperativeKernel(reinterpret_cast<const void*>(&k_csr),
                               dim3(SCAN_NB), dim3(256), args, 0, stream);
  }

  // layer 0: node f32 -> xt1 in B (inline bf16 convert); x1 -> XN
  k_gemm_t<true><<<1024, 256, 0, stream>>>((const void*)node, B, W, a, s_src, s_dst);
  k_agg<<<2048, 256, 0, stream>>>(row_ptr, cse, s_src, s_dst, s_rel, B, XN,
                                  node, XN, out, 0);

  // layer 1: XN(x1) -> xt2 in B (keeps x1); fused finale writes out
  k_gemm_t<false><<<1024, 256, 0, stream>>>((const void*)XN, B, W + DIM*DIM, a + 3*DIM,
                                            s_src, s_dst);
  k_agg<<<2048, 256, 0, stream>>>(row_ptr, cse, s_src, s_dst, s_rel + NREL, B, nullptr,
                                  node, XN, out, 1);
}

// Round 2
// 275.781 us; speedup vs baseline: 2.2461x; 2.2461x over previous
//
#include <hip/hip_runtime.h>
#include <hip/hip_bf16.h>
#include <cmath>

#define NODES 150000
#define DIM 64
#define EDGES 1200000
#define NREL 32
#define NLAYERS 2
#define NND (NODES*DIM)
#define SCAN_NB ((NODES + 255)/256)   // 586
#define RBLK (NODES/16)               // 9375 row-blocks of 16 (gemm)
#define NRB4 (NODES/4)                // 37500 row-quads (agg)

typedef __hip_bfloat16 bf16;
typedef unsigned short ushort16;
typedef __attribute__((ext_vector_type(8))) short bf16x8;  // MFMA A/B frag (4 VGPRs)
typedef __attribute__((ext_vector_type(4))) float f32x4;   // MFMA C/D frag

__device__ __forceinline__ float b2f(bf16 v){ return __bfloat162float(v); }
__device__ __forceinline__ short f2bs(float f){
  bf16 h = __float2bfloat16(f);
  return *(short*)&h;
}

// sentinel: encode ws_size (MB) into output (tripwire only)
__global__ void __launch_bounds__(256) k_sentinel(float* __restrict__ out, float wsmb){
  int i = blockIdx.x*256 + threadIdx.x;
  if (i < NND) out[i] = wsmb;
}

// pure histogram: pl[e] = per-edge local slot (atomic return). count[] pre-zeroed.
// (node->bf16 conversion removed: layer-0 gemm reads f32 directly)
__global__ void __launch_bounds__(256) k_hist(const int* __restrict__ dst,
                                              int* __restrict__ count,
                                              ushort16* __restrict__ pl){
  int tid0 = blockIdx.x*256 + threadIdx.x;
  int stride = gridDim.x*256;
  for (int e = tid0; e < EDGES; e += stride)
    pl[e] = (ushort16)atomicAdd(&count[dst[e]], 1);
}

// scan phase 1: per-block (256 nodes) exclusive scan + block sum
__global__ void __launch_bounds__(256) k_scan1(const int* __restrict__ count,
                                               int* __restrict__ lscan,
                                               int* __restrict__ bsum){
  int tid = threadIdx.x;
  int i = blockIdx.x*256 + tid;
  int c = (i < NODES) ? count[i] : 0;
  __shared__ int s[256];
  s[tid] = c;
  __syncthreads();
  #pragma unroll
  for (int off = 1; off < 256; off <<= 1){
    int t = (tid >= off) ? s[tid - off] : 0;
    __syncthreads();
    s[tid] += t;
    __syncthreads();
  }
  if (i < NODES) lscan[i] = s[tid] - c;
  if (tid == 255) bsum[blockIdx.x] = s[255];
}

// scan phase 2: single block scans the SCAN_NB block sums (exclusive, in place)
__global__ void __launch_bounds__(1024) k_scan2(int* __restrict__ bsum){
  int tid = threadIdx.x;
  int c = (tid < SCAN_NB) ? bsum[tid] : 0;
  __shared__ int s[1024];
  s[tid] = c;
  __syncthreads();
  #pragma unroll
  for (int off = 1; off < 1024; off <<= 1){
    int t = (tid >= off) ? s[tid - off] : 0;
    __syncthreads();
    s[tid] += t;
    __syncthreads();
  }
  if (tid < SCAN_NB) bsum[tid] = s[tid] - c;
}

// scan phase 3: row_ptr = lscan + bsum[block]; cap entry
__global__ void __launch_bounds__(256) k_scan3(const int* __restrict__ lscan,
                                               const int* __restrict__ bsum,
                                               int* __restrict__ row_ptr){
  int i = blockIdx.x*256 + threadIdx.x;
  if (i < NODES) row_ptr[i] = lscan[i] + bsum[i >> 8];
  if (i == NODES) row_ptr[NODES] = EDGES;
}

// atomic-free scatter: p = row_ptr[dst] + pl (unique)
__global__ void __launch_bounds__(256) k_build(const int* __restrict__ src,
                                               const int* __restrict__ dst,
                                               const int* __restrict__ et,
                                               const ushort16* __restrict__ pl,
                                               const int* __restrict__ row_ptr,
                                               unsigned* __restrict__ cse){
  int tid0 = blockIdx.x*256 + threadIdx.x;
  int stride = gridDim.x*256;
  for (int e = tid0; e < EDGES; e += stride){
    int p = row_ptr[dst[e]] + (int)pl[e];
    cse[p] = (unsigned)src[e] | ((unsigned)et[e] << 18);
  }
}

// both layers' s_rel in one launch: block l computes s_rel[l][r]
__global__ void k_relboth(const float* __restrict__ Wr, const float* __restrict__ a,
                          const float* __restrict__ rel, float* __restrict__ s_rel){
  int l = blockIdx.x;
  const float* Wr_l  = Wr  + l*DIM*DIM;
  const float* a_l   = a   + l*3*DIM;
  const float* rel_l = rel + l*NREL*DIM;
  __shared__ float w[DIM];
  int t = threadIdx.x; // 64 threads
  float s = 0.f;
  for (int j = 0; j < DIM; j++) s += Wr_l[t*DIM + j] * a_l[DIM + j];
  w[t] = s;
  __syncthreads();
  if (t < NREL){
    float r = 0.f;
    for (int k = 0; k < DIM; k++) r += rel_l[t*DIM + k] * w[k];
    s_rel[l*NREL + t] = r;
  }
}

__device__ __forceinline__ bf16x8 pack8(float4 lo, float4 hi){
  bf16x8 r;
  ((short*)&r)[0] = f2bs(lo.x); ((short*)&r)[1] = f2bs(lo.y);
  ((short*)&r)[2] = f2bs(lo.z); ((short*)&r)[3] = f2bs(lo.w);
  ((short*)&r)[4] = f2bs(hi.x); ((short*)&r)[5] = f2bs(hi.y);
  ((short*)&r)[6] = f2bs(hi.z); ((short*)&r)[7] = f2bs(hi.w);
  return r;
}

// per layer, MFMA: xt = x @ W. F32IN=true reads f32 rows (layer 0: node_emb
// directly, converting inline with the same __float2bfloat16 rounding the old
// conversion pass used -> bit-identical). s_src/s_dst from accumulators.
template<bool F32IN>
__global__ void __launch_bounds__(256) k_gemm_t(const void* __restrict__ xin_,
                                                bf16* __restrict__ xt,
                                                const float* __restrict__ W_l,
                                                const float* __restrict__ a_l,
                                                float* __restrict__ s_src_a,
                                                float* __restrict__ s_dst_a){
  __shared__ float Ws[DIM*DIM];   // 16 KB staged f32 W
  int tid = threadIdx.x;
  for (int i = tid; i < DIM*DIM; i += 256) Ws[i] = W_l[i];
  __syncthreads();

  int lane = tid & 63;
  int l15  = lane & 15;
  int quad = lane >> 4;

  bf16x8 bfrag[4][2];
  #pragma unroll
  for (int nt = 0; nt < 4; nt++)
    #pragma unroll
    for (int kh = 0; kh < 2; kh++)
      #pragma unroll
      for (int j = 0; j < 8; j++){
        int k = kh*32 + quad*8 + j;
        ((short*)&bfrag[nt][kh])[j] = f2bs(Ws[k*DIM + nt*16 + l15]);
      }

  float asrc[4], adst[4];
  #pragma unroll
  for (int nt = 0; nt < 4; nt++){
    asrc[nt] = a_l[nt*16 + l15];
    adst[nt] = a_l[2*DIM + nt*16 + l15];
  }

  int gw = blockIdx.x*4 + (tid >> 6);
  int nw = gridDim.x*4;
  for (int rb = gw; rb < RBLK; rb += nw){
    int r0 = rb*16;
    const size_t abase = (size_t)(r0 + l15)*DIM + quad*8;
    bf16x8 a0, a1;
    if constexpr (F32IN){
      const float* xf = (const float*)xin_ + abase;
      float4 f0 = *(const float4*)(xf);
      float4 f1 = *(const float4*)(xf + 4);
      float4 f2 = *(const float4*)(xf + 32);
      float4 f3 = *(const float4*)(xf + 36);
      a0 = pack8(f0, f1);
      a1 = pack8(f2, f3);
    } else {
      const bf16* xb = (const bf16*)xin_;
      a0 = *(const bf16x8*)(xb + abase);
      a1 = *(const bf16x8*)(xb + abase + 32);
    }

    f32x4 acc[4];
    #pragma unroll
    for (int nt = 0; nt < 4; nt++){
      acc[nt] = (f32x4){0.f, 0.f, 0.f, 0.f};
      acc[nt] = __builtin_amdgcn_mfma_f32_16x16x32_bf16(a0, bfrag[nt][0], acc[nt], 0, 0, 0);
      acc[nt] = __builtin_amdgcn_mfma_f32_16x16x32_bf16(a1, bfrag[nt][1], acc[nt], 0, 0, 0);
    }

    float p[4], q[4];
    #pragma unroll
    for (int i = 0; i < 4; i++){
      p[i] = acc[0][i]*asrc[0] + acc[1][i]*asrc[1] + acc[2][i]*asrc[2] + acc[3][i]*asrc[3];
      q[i] = acc[0][i]*adst[0] + acc[1][i]*adst[1] + acc[2][i]*adst[2] + acc[3][i]*adst[3];
      #pragma unroll
      for (int off = 8; off > 0; off >>= 1){
        p[i] += __shfl_xor(p[i], off, 64);
        q[i] += __shfl_xor(q[i], off, 64);
      }
    }
    if (l15 < 4){
      float pv = (l15 == 0) ? p[0] : (l15 == 1) ? p[1] : (l15 == 2) ? p[2] : p[3];
      float qv = (l15 == 0) ? q[0] : (l15 == 1) ? q[1] : (l15 == 2) ? q[2] : q[3];
      int r = r0 + quad*4 + l15;
      s_src_a[r] = pv;
      s_dst_a[r] = qv;
    }

    #pragma unroll
    for (int nt = 0; nt < 4; nt++)
      #pragma unroll
      for (int i = 0; i < 4; i++)
        xt[(size_t)(r0 + quad*4 + i)*DIM + nt*16 + l15] = __float2bfloat16(acc[nt][i]);
  }
}

// per layer: FOUR rows per wave (16-lane groups). Lane l15 of group grp covers
// columns [l15*4, l15*4+4) of row rb*4+grp. Per edge: one 8 B load (4 bf16)
// feeds 4 fmas; 2 shfls serve the whole group. 4 independent row chains per
// wave + MLP=4 gathers per group = 16 loads in flight per wave.
// Guard-free: idle scoring lanes carry wl=0 -> weight-0 row-0 gathers.
// All shfl sources stay inside the lane's own (active) group, so inter-group
// trip-count divergence is safe.
// mode0: write xnext only. mode1: fused finale out=(node+x1+x2)/3, no xnext.
__global__ void __launch_bounds__(256) k_agg(const int* __restrict__ row_ptr,
                                             const unsigned* __restrict__ cse,
                                             const float* __restrict__ s_src_a,
                                             const float* __restrict__ s_dst_a,
                                             const float* __restrict__ s_rel,
                                             const bf16* __restrict__ xt,
                                             bf16* __restrict__ xnext,
                                             const float* __restrict__ node,
                                             const bf16* __restrict__ x1,
                                             float* __restrict__ out, int mode){
  int lane = threadIdx.x & 63;
  int grp  = lane >> 4;
  int l15  = lane & 15;
  int gw = blockIdx.x*4 + (threadIdx.x >> 6);
  int nw = gridDim.x*4;
  for (int rb = gw; rb < NRB4; rb += nw){
    int row = rb*4 + grp;
    int beg = row_ptr[row], end = row_ptr[row+1];
    float sdst = s_dst_a[row];
    float h0 = 0.f, h1 = 0.f, h2 = 0.f, h3 = 0.f;
    float wsuml = 0.f;
    for (int jb = beg; jb < end; jb += 16){
      int n = end - jb; if (n > 16) n = 16;
      unsigned pkv = 0u; float wl = 0.f;
      if (l15 < n){
        pkv = cse[jb + l15];
        int sl = (int)(pkv & 0x3FFFFu);
        int rl = (int)(pkv >> 18);
        float e = s_src_a[sl] + s_rel[rl] + sdst;
        e = e > 0.f ? e : 0.2f*e;
        wl = __expf(e);
      }
      wsuml += wl;
      int nk = (n + 3) & ~3;
      for (int j0 = 0; j0 < nk; j0 += 4){
        unsigned lo[4], hi[4];
        float wg[4];
        #pragma unroll
        for (int u = 0; u < 4; u++){
          int srcl = grp*16 + j0 + u;               // within this lane's group
          int s    = (int)(__shfl(pkv, srcl, 64) & 0x3FFFFu);
          wg[u]    = __shfl(wl, srcl, 64);
          uint2 d  = *(const uint2*)(xt + (size_t)s*DIM + l15*4);  // 4 bf16
          lo[u] = d.x; hi[u] = d.y;
        }
        #pragma unroll
        for (int u = 0; u < 4; u++){
          h0 = fmaf(wg[u], __uint_as_float(lo[u] << 16),          h0);
          h1 = fmaf(wg[u], __uint_as_float(lo[u] & 0xffff0000u),  h1);
          h2 = fmaf(wg[u], __uint_as_float(hi[u] << 16),          h2);
          h3 = fmaf(wg[u], __uint_as_float(hi[u] & 0xffff0000u),  h3);
        }
      }
    }
    // group-wide (16-lane) reductions: xor masks 1,2,4,8 stay inside the group
    float wsum = wsuml;
    #pragma unroll
    for (int off = 8; off > 0; off >>= 1) wsum += __shfl_xor(wsum, off, 64);

    float inv = 1.f / (wsum + 1e-10f);
    float v0 = h0*inv, v1 = h1*inv, v2 = h2*inv, v3 = h3*inv;
    v0 = v0 > 0.f ? v0 : expm1f(v0);
    v1 = v1 > 0.f ? v1 : expm1f(v1);
    v2 = v2 > 0.f ? v2 : expm1f(v2);
    v3 = v3 > 0.f ? v3 : expm1f(v3);
    float ss = v0*v0 + v1*v1 + v2*v2 + v3*v3;
    #pragma unroll
    for (int off = 8; off > 0; off >>= 1) ss += __shfl_xor(ss, off, 64);
    float rinv = 1.f / fmaxf(sqrtf(ss), 1e-12f);
    float x0 = v0*rinv, x1v = v1*rinv, x2 = v2*rinv, x3 = v3*rinv;

    size_t i = (size_t)row*DIM + l15*4;
    if (mode == 0){
      ushort16 st[4] = { (ushort16)((unsigned)f2bs(x0) & 0xffffu),
                         (ushort16)((unsigned)f2bs(x1v) & 0xffffu),
                         (ushort16)((unsigned)f2bs(x2) & 0xffffu),
                         (ushort16)((unsigned)f2bs(x3) & 0xffffu) };
      uint2 pk;
      pk.x = (unsigned)st[0] | ((unsigned)st[1] << 16);
      pk.y = (unsigned)st[2] | ((unsigned)st[3] << 16);
      *(uint2*)(xnext + i) = pk;
    } else {
      float4 nd = *(const float4*)(node + i);
      uint2 xo  = *(const uint2*)(x1 + i);
      float o0 = (nd.x + __uint_as_float(xo.x << 16)         + x0 ) * (1.f/3.f);
      float o1 = (nd.y + __uint_as_float(xo.x & 0xffff0000u) + x1v) * (1.f/3.f);
      float o2 = (nd.z + __uint_as_float(xo.y << 16)         + x2 ) * (1.f/3.f);
      float o3 = (nd.w + __uint_as_float(xo.y & 0xffff0000u) + x3 ) * (1.f/3.f);
      *(float4*)(out + i) = make_float4(o0, o1, o2, o3);
    }
  }
}

extern "C" void kernel_launch(void* const* d_in, const int* in_sizes, int n_in,
                              void* d_out, int out_size, void* d_ws, size_t ws_size,
                              hipStream_t stream){
  const float* node = (const float*)d_in[0];
  const float* W    = (const float*)d_in[1];
  const float* Wr   = (const float*)d_in[2];
  const float* a    = (const float*)d_in[3];
  const float* rel  = (const float*)d_in[4];
  const int*   ei   = (const int*)d_in[5];
  const int*   et   = (const int*)d_in[6];
  const int* src = ei;
  const int* dst = ei + EDGES;
  float* out = (float*)d_out;

  // ---- workspace layout (~48 MB; proven to fit) ----
  char* w = (char*)d_ws;
  size_t off = 0;
  bf16* B  = (bf16*)(w + off); off += (size_t)NND*2;             // 19.2 MB xt1, then xt2
  bf16* XN = (bf16*)(w + off); off += (size_t)NND*2;             // 19.2 MB x1
  unsigned* cse = (unsigned*)(w + off); off += (size_t)EDGES*4;  //  4.8 MB CSR packed
  ushort16* pl = (ushort16*)(w + off); off += (size_t)EDGES*2;   //  2.4 MB per-edge local slot
  int* row_ptr = (int*)(w + off); off += (size_t)(NODES+1)*4;    //  0.6 MB
  int* count   = (int*)(w + off); off += (size_t)NODES*4;        //  0.6 MB
  int* lscan   = (int*)(w + off); off += (size_t)NODES*4;        //  0.6 MB
  int* bsum    = (int*)(w + off); off += (size_t)SCAN_NB*4;      //  2.3 KB
  float* s_src = (float*)(w + off); off += (size_t)NODES*4;      //  0.6 MB
  float* s_dst = (float*)(w + off); off += (size_t)NODES*4;      //  0.6 MB
  float* s_rel = (float*)(w + off); off += 2*NREL*4;

  if (ws_size < off){
    k_sentinel<<<(NND + 255)/256, 256, 0, stream>>>(out, (float)ws_size * 1e-6f);
    return;
  }

  // one-time CSR build (layer-invariant), single atomic pass (multi-kernel:
  // cooperative fusion measured 5x slower -- occupancy-capped, round 1)
  hipMemsetAsync(count, 0, (size_t)NODES*4, stream);
  k_relboth <<<2, 64, 0, stream>>>(Wr, a, rel, s_rel);
  k_hist    <<<4096, 256, 0, stream>>>(dst, count, pl);
  k_scan1   <<<SCAN_NB, 256, 0, stream>>>(count, lscan, bsum);
  k_scan2   <<<1, 1024, 0, stream>>>(bsum);
  k_scan3   <<<SCAN_NB + 1, 256, 0, stream>>>(lscan, bsum, row_ptr);
  k_build   <<<4096, 256, 0, stream>>>(src, dst, et, pl, row_ptr, cse);

  // layer 0: node f32 -> xt1 in B (inline bf16 convert, no pre-pass); x1 -> XN
  k_gemm_t<true><<<1024, 256, 0, stream>>>((const void*)node, B, W, a, s_src, s_dst);
  k_agg<<<2048, 256, 0, stream>>>(row_ptr, cse, s_src, s_dst, s_rel, B, XN,
                                  node, XN, out, 0);

  // layer 1: XN(x1) -> xt2 in B (keeps x1); fused finale writes out
  k_gemm_t<false><<<1024, 256, 0, stream>>>((const void*)XN, B, W + DIM*DIM, a + 3*DIM,
                                            s_src, s_dst);
  k_agg<<<2048, 256, 0, stream>>>(row_ptr, cse, s_src, s_dst, s_rel + NREL, B, nullptr,
                                  node, XN, out, 1);
}

// Round 3
// 274.257 us; speedup vs baseline: 2.2585x; 1.0056x over previous
//
#include <hip/hip_runtime.h>
#include <hip/hip_bf16.h>
#include <cmath>

#define NODES 150000
#define DIM 64
#define EDGES 1200000
#define NREL 32
#define NLAYERS 2
#define NND (NODES*DIM)
#define SCAN_NB ((NODES + 255)/256)   // 586
#define RBLK (NODES/16)               // 9375 row-blocks of 16 (gemm)
#define NRB4 (NODES/4)                // 37500 row-quads (agg)
#define EBLK ((EDGES + 255)/256)      // 4688 edge blocks (1 edge/thread)
#define GEMM_NB 1024                  // gemm-0 blocks inside fused launch

typedef __hip_bfloat16 bf16;
typedef unsigned short ushort16;
typedef __attribute__((ext_vector_type(8))) short bf16x8;  // MFMA A/B frag (4 VGPRs)
typedef __attribute__((ext_vector_type(4))) float f32x4;   // MFMA C/D frag

__device__ __forceinline__ float b2f(bf16 v){ return __bfloat162float(v); }
__device__ __forceinline__ short f2bs(float f){
  bf16 h = __float2bfloat16(f);
  return *(short*)&h;
}

// sentinel: encode ws_size (MB) into output (tripwire only)
__global__ void __launch_bounds__(256) k_sentinel(float* __restrict__ out, float wsmb){
  int i = blockIdx.x*256 + threadIdx.x;
  if (i < NND) out[i] = wsmb;
}

// pre-pass: blocks 0..585 zero count; blocks 586,587 compute s_rel (layer = bid-586)
__global__ void __launch_bounds__(256) k_pre(int* __restrict__ count,
                                             const float* __restrict__ Wr,
                                             const float* __restrict__ a,
                                             const float* __restrict__ rel,
                                             float* __restrict__ s_rel){
  int bid = blockIdx.x, tid = threadIdx.x;
  if (bid < SCAN_NB){
    int i = bid*256 + tid;
    if (i < NODES) count[i] = 0;
  } else {
    int l = bid - SCAN_NB;
    const float* Wr_l  = Wr  + l*DIM*DIM;
    const float* a_l   = a   + l*3*DIM;
    const float* rel_l = rel + l*NREL*DIM;
    __shared__ float w[DIM];
    if (tid < DIM){
      float s = 0.f;
      for (int j = 0; j < DIM; j++) s += Wr_l[tid*DIM + j] * a_l[DIM + j];
      w[tid] = s;
    }
    __syncthreads();
    if (tid < NREL){
      float r = 0.f;
      for (int k = 0; k < DIM; k++) r += rel_l[tid*DIM + k] * w[k];
      s_rel[l*NREL + tid] = r;
    }
  }
}

__device__ __forceinline__ bf16x8 pack8(float4 lo, float4 hi){
  bf16x8 r;
  ((short*)&r)[0] = f2bs(lo.x); ((short*)&r)[1] = f2bs(lo.y);
  ((short*)&r)[2] = f2bs(lo.z); ((short*)&r)[3] = f2bs(lo.w);
  ((short*)&r)[4] = f2bs(hi.x); ((short*)&r)[5] = f2bs(hi.y);
  ((short*)&r)[6] = f2bs(hi.z); ((short*)&r)[7] = f2bs(hi.w);
  return r;
}

// gemm body: xt = x @ W (MFMA 16x16x32), s_src/s_dst from accumulators.
// F32IN: read f32 rows + inline bf16 convert (layer 0, bit-identical rounding).
template<bool F32IN>
__device__ __forceinline__ void gemm_body(int gb, int ngb,
                                          const void* __restrict__ xin_,
                                          bf16* __restrict__ xt,
                                          const float* __restrict__ W_l,
                                          const float* __restrict__ a_l,
                                          float* __restrict__ s_src_a,
                                          float* __restrict__ s_dst_a){
  __shared__ float Ws[DIM*DIM];   // 16 KB staged f32 W
  int tid = threadIdx.x;
  for (int i = tid; i < DIM*DIM; i += 256) Ws[i] = W_l[i];
  __syncthreads();

  int lane = tid & 63;
  int l15  = lane & 15;
  int quad = lane >> 4;

  bf16x8 bfrag[4][2];
  #pragma unroll
  for (int nt = 0; nt < 4; nt++)
    #pragma unroll
    for (int kh = 0; kh < 2; kh++)
      #pragma unroll
      for (int j = 0; j < 8; j++){
        int k = kh*32 + quad*8 + j;
        ((short*)&bfrag[nt][kh])[j] = f2bs(Ws[k*DIM + nt*16 + l15]);
      }

  float asrc[4], adst[4];
  #pragma unroll
  for (int nt = 0; nt < 4; nt++){
    asrc[nt] = a_l[nt*16 + l15];
    adst[nt] = a_l[2*DIM + nt*16 + l15];
  }

  int gw = gb*4 + (tid >> 6);
  int nw = ngb*4;
  for (int rb = gw; rb < RBLK; rb += nw){
    int r0 = rb*16;
    const size_t abase = (size_t)(r0 + l15)*DIM + quad*8;
    bf16x8 a0, a1;
    if constexpr (F32IN){
      const float* xf = (const float*)xin_ + abase;
      float4 f0 = *(const float4*)(xf);
      float4 f1 = *(const float4*)(xf + 4);
      float4 f2 = *(const float4*)(xf + 32);
      float4 f3 = *(const float4*)(xf + 36);
      a0 = pack8(f0, f1);
      a1 = pack8(f2, f3);
    } else {
      const bf16* xb = (const bf16*)xin_;
      a0 = *(const bf16x8*)(xb + abase);
      a1 = *(const bf16x8*)(xb + abase + 32);
    }

    f32x4 acc[4];
    #pragma unroll
    for (int nt = 0; nt < 4; nt++){
      acc[nt] = (f32x4){0.f, 0.f, 0.f, 0.f};
      acc[nt] = __builtin_amdgcn_mfma_f32_16x16x32_bf16(a0, bfrag[nt][0], acc[nt], 0, 0, 0);
      acc[nt] = __builtin_amdgcn_mfma_f32_16x16x32_bf16(a1, bfrag[nt][1], acc[nt], 0, 0, 0);
    }

    float p[4], q[4];
    #pragma unroll
    for (int i = 0; i < 4; i++){
      p[i] = acc[0][i]*asrc[0] + acc[1][i]*asrc[1] + acc[2][i]*asrc[2] + acc[3][i]*asrc[3];
      q[i] = acc[0][i]*adst[0] + acc[1][i]*adst[1] + acc[2][i]*adst[2] + acc[3][i]*adst[3];
      #pragma unroll
      for (int off = 8; off > 0; off >>= 1){
        p[i] += __shfl_xor(p[i], off, 64);
        q[i] += __shfl_xor(q[i], off, 64);
      }
    }
    if (l15 < 4){
      float pv = (l15 == 0) ? p[0] : (l15 == 1) ? p[1] : (l15 == 2) ? p[2] : p[3];
      float qv = (l15 == 0) ? q[0] : (l15 == 1) ? q[1] : (l15 == 2) ? q[2] : q[3];
      int r = r0 + quad*4 + l15;
      s_src_a[r] = pv;
      s_dst_a[r] = qv;
    }

    #pragma unroll
    for (int nt = 0; nt < 4; nt++)
      #pragma unroll
      for (int i = 0; i < 4; i++)
        xt[(size_t)(r0 + quad*4 + i)*DIM + nt*16 + l15] = __float2bfloat16(acc[nt][i]);
  }
}

// fused: blocks [0,GEMM_NB) run layer-0 gemm (f32 in); blocks [GEMM_NB,..) run
// the histogram (1 edge/thread, device atomic w/ return). Independent work —
// gemm's BW/MFMA hides in the histogram's atomic-latency shadow (hist was
// 0.6% VALU, 11% HBM, 65% occ). gemm blocks first so they're resident early.
__global__ void __launch_bounds__(256) k_histgemm(const int* __restrict__ dst,
                                                  int* __restrict__ count,
                                                  ushort16* __restrict__ pl,
                                                  const float* __restrict__ node,
                                                  bf16* __restrict__ xt,
                                                  const float* __restrict__ W_l,
                                                  const float* __restrict__ a_l,
                                                  float* __restrict__ s_src_a,
                                                  float* __restrict__ s_dst_a){
  if (blockIdx.x < GEMM_NB){
    gemm_body<true>(blockIdx.x, GEMM_NB, (const void*)node, xt, W_l, a_l,
                    s_src_a, s_dst_a);
  } else {
    int e = (blockIdx.x - GEMM_NB)*256 + threadIdx.x;
    if (e < EDGES)
      pl[e] = (ushort16)atomicAdd(&count[dst[e]], 1);
  }
}

// scan phase 1: per-block (256 nodes) exclusive scan + block sum
__global__ void __launch_bounds__(256) k_scan1(const int* __restrict__ count,
                                               int* __restrict__ lscan,
                                               int* __restrict__ bsum){
  int tid = threadIdx.x;
  int i = blockIdx.x*256 + tid;
  int c = (i < NODES) ? count[i] : 0;
  __shared__ int s[256];
  s[tid] = c;
  __syncthreads();
  #pragma unroll
  for (int off = 1; off < 256; off <<= 1){
    int t = (tid >= off) ? s[tid - off] : 0;
    __syncthreads();
    s[tid] += t;
    __syncthreads();
  }
  if (i < NODES) lscan[i] = s[tid] - c;
  if (tid == 255) bsum[blockIdx.x] = s[255];
}

// scan phase 2: single block scans the SCAN_NB block sums (exclusive, in place)
__global__ void __launch_bounds__(1024) k_scan2(int* __restrict__ bsum){
  int tid = threadIdx.x;
  int c = (tid < SCAN_NB) ? bsum[tid] : 0;
  __shared__ int s[1024];
  s[tid] = c;
  __syncthreads();
  #pragma unroll
  for (int off = 1; off < 1024; off <<= 1){
    int t = (tid >= off) ? s[tid - off] : 0;
    __syncthreads();
    s[tid] += t;
    __syncthreads();
  }
  if (tid < SCAN_NB) bsum[tid] = s[tid] - c;
}

// atomic-free scatter: p = (lscan[d] + bsum[d>>8]) + pl  (row_ptr inlined;
// lscan/bsum are L2-hot -> scan3 kernel + row_ptr array eliminated)
__global__ void __launch_bounds__(256) k_build(const int* __restrict__ src,
                                               const int* __restrict__ dst,
                                               const int* __restrict__ et,
                                               const ushort16* __restrict__ pl,
                                               const int* __restrict__ lscan,
                                               const int* __restrict__ bsum,
                                               unsigned* __restrict__ cse){
  int e = blockIdx.x*256 + threadIdx.x;
  if (e < EDGES){
    int d = dst[e];
    int p = lscan[d] + bsum[d >> 8] + (int)pl[e];
    cse[p] = (unsigned)src[e] | ((unsigned)et[e] << 18);
  }
}

__device__ __forceinline__ int rowptr_of(const int* __restrict__ lscan,
                                         const int* __restrict__ bsum, int i){
  return (i < NODES) ? (lscan[i] + bsum[i >> 8]) : EDGES;
}

// per layer: FOUR rows per wave (16-lane groups). Lane l15 of group grp covers
// columns [l15*4, l15*4+4) of row rb*4+grp. Per edge: one 8 B load (4 bf16)
// feeds 4 fmas; 2 shfls serve the whole group. 4 independent row chains per
// wave + MLP=4 gathers per group = 16 loads in flight per wave.
// Guard-free: idle scoring lanes carry wl=0 -> weight-0 row-0 gathers.
// All shfl sources stay inside the lane's own (active) group, so inter-group
// trip-count divergence is safe.
// mode0: write xnext only. mode1: fused finale out=(node+x1+x2)/3, no xnext.
__global__ void __launch_bounds__(256) k_agg(const int* __restrict__ lscan,
                                             const int* __restrict__ bsum,
                                             const unsigned* __restrict__ cse,
                                             const float* __restrict__ s_src_a,
                                             const float* __restrict__ s_dst_a,
                                             const float* __restrict__ s_rel,
                                             const bf16* __restrict__ xt,
                                             bf16* __restrict__ xnext,
                                             const float* __restrict__ node,
                                             const bf16* __restrict__ x1,
                                             float* __restrict__ out, int mode){
  int lane = threadIdx.x & 63;
  int grp  = lane >> 4;
  int l15  = lane & 15;
  int gw = blockIdx.x*4 + (threadIdx.x >> 6);
  int nw = gridDim.x*4;
  for (int rb = gw; rb < NRB4; rb += nw){
    int row = rb*4 + grp;
    int beg = rowptr_of(lscan, bsum, row);
    int end = rowptr_of(lscan, bsum, row + 1);
    float sdst = s_dst_a[row];
    float h0 = 0.f, h1 = 0.f, h2 = 0.f, h3 = 0.f;
    float wsuml = 0.f;
    for (int jb = beg; jb < end; jb += 16){
      int n = end - jb; if (n > 16) n = 16;
      unsigned pkv = 0u; float wl = 0.f;
      if (l15 < n){
        pkv = cse[jb + l15];
        int sl = (int)(pkv & 0x3FFFFu);
        int rl = (int)(pkv >> 18);
        float e = s_src_a[sl] + s_rel[rl] + sdst;
        e = e > 0.f ? e : 0.2f*e;
        wl = __expf(e);
      }
      wsuml += wl;
      int nk = (n + 3) & ~3;
      for (int j0 = 0; j0 < nk; j0 += 4){
        unsigned lo[4], hi[4];
        float wg[4];
        #pragma unroll
        for (int u = 0; u < 4; u++){
          int srcl = grp*16 + j0 + u;               // within this lane's group
          int s    = (int)(__shfl(pkv, srcl, 64) & 0x3FFFFu);
          wg[u]    = __shfl(wl, srcl, 64);
          uint2 d  = *(const uint2*)(xt + (size_t)s*DIM + l15*4);  // 4 bf16
          lo[u] = d.x; hi[u] = d.y;
        }
        #pragma unroll
        for (int u = 0; u < 4; u++){
          h0 = fmaf(wg[u], __uint_as_float(lo[u] << 16),          h0);
          h1 = fmaf(wg[u], __uint_as_float(lo[u] & 0xffff0000u),  h1);
          h2 = fmaf(wg[u], __uint_as_float(hi[u] << 16),          h2);
          h3 = fmaf(wg[u], __uint_as_float(hi[u] & 0xffff0000u),  h3);
        }
      }
    }
    // group-wide (16-lane) reductions: xor masks 1,2,4,8 stay inside the group
    float wsum = wsuml;
    #pragma unroll
    for (int off = 8; off > 0; off >>= 1) wsum += __shfl_xor(wsum, off, 64);

    float inv = 1.f / (wsum + 1e-10f);
    float v0 = h0*inv, v1 = h1*inv, v2 = h2*inv, v3 = h3*inv;
    v0 = v0 > 0.f ? v0 : expm1f(v0);
    v1 = v1 > 0.f ? v1 : expm1f(v1);
    v2 = v2 > 0.f ? v2 : expm1f(v2);
    v3 = v3 > 0.f ? v3 : expm1f(v3);
    float ss = v0*v0 + v1*v1 + v2*v2 + v3*v3;
    #pragma unroll
    for (int off = 8; off > 0; off >>= 1) ss += __shfl_xor(ss, off, 64);
    float rinv = 1.f / fmaxf(sqrtf(ss), 1e-12f);
    float x0 = v0*rinv, x1v = v1*rinv, x2 = v2*rinv, x3 = v3*rinv;

    size_t i = (size_t)row*DIM + l15*4;
    if (mode == 0){
      ushort16 st[4] = { (ushort16)((unsigned)f2bs(x0) & 0xffffu),
                         (ushort16)((unsigned)f2bs(x1v) & 0xffffu),
                         (ushort16)((unsigned)f2bs(x2) & 0xffffu),
                         (ushort16)((unsigned)f2bs(x3) & 0xffffu) };
      uint2 pk;
      pk.x = (unsigned)st[0] | ((unsigned)st[1] << 16);
      pk.y = (unsigned)st[2] | ((unsigned)st[3] << 16);
      *(uint2*)(xnext + i) = pk;
    } else {
      float4 nd = *(const float4*)(node + i);
      uint2 xo  = *(const uint2*)(x1 + i);
      float o0 = (nd.x + __uint_as_float(xo.x << 16)         + x0 ) * (1.f/3.f);
      float o1 = (nd.y + __uint_as_float(xo.x & 0xffff0000u) + x1v) * (1.f/3.f);
      float o2 = (nd.z + __uint_as_float(xo.y << 16)         + x2 ) * (1.f/3.f);
      float o3 = (nd.w + __uint_as_float(xo.y & 0xffff0000u) + x3 ) * (1.f/3.f);
      *(float4*)(out + i) = make_float4(o0, o1, o2, o3);
    }
  }
}

// layer-1 gemm (bf16 input), standalone launch
__global__ void __launch_bounds__(256) k_gemm1(const bf16* __restrict__ xin,
                                               bf16* __restrict__ xt,
                                               const float* __restrict__ W_l,
                                               const float* __restrict__ a_l,
                                               float* __restrict__ s_src_a,
                                               float* __restrict__ s_dst_a){
  gemm_body<false>(blockIdx.x, gridDim.x, (const void*)xin, xt, W_l, a_l,
                   s_src_a, s_dst_a);
}

extern "C" void kernel_launch(void* const* d_in, const int* in_sizes, int n_in,
                              void* d_out, int out_size, void* d_ws, size_t ws_size,
                              hipStream_t stream){
  const float* node = (const float*)d_in[0];
  const float* W    = (const float*)d_in[1];
  const float* Wr   = (const float*)d_in[2];
  const float* a    = (const float*)d_in[3];
  const float* rel  = (const float*)d_in[4];
  const int*   ei   = (const int*)d_in[5];
  const int*   et   = (const int*)d_in[6];
  const int* src = ei;
  const int* dst = ei + EDGES;
  float* out = (float*)d_out;

  // ---- workspace layout (~47 MB; proven to fit) ----
  char* w = (char*)d_ws;
  size_t off = 0;
  bf16* B  = (bf16*)(w + off); off += (size_t)NND*2;             // 19.2 MB xt1, then xt2
  bf16* XN = (bf16*)(w + off); off += (size_t)NND*2;             // 19.2 MB x1
  unsigned* cse = (unsigned*)(w + off); off += (size_t)EDGES*4;  //  4.8 MB CSR packed
  ushort16* pl = (ushort16*)(w + off); off += (size_t)EDGES*2;   //  2.4 MB per-edge local slot
  int* count   = (int*)(w + off); off += (size_t)NODES*4;        //  0.6 MB
  int* lscan   = (int*)(w + off); off += (size_t)NODES*4;        //  0.6 MB
  int* bsum    = (int*)(w + off); off += (size_t)SCAN_NB*4;      //  2.3 KB
  float* s_src = (float*)(w + off); off += (size_t)NODES*4;      //  0.6 MB
  float* s_dst = (float*)(w + off); off += (size_t)NODES*4;      //  0.6 MB
  float* s_rel = (float*)(w + off); off += 2*NREL*4;

  if (ws_size < off){
    k_sentinel<<<(NND + 255)/256, 256, 0, stream>>>(out, (float)ws_size * 1e-6f);
    return;
  }

  // pre: zero count + both layers' s_rel (1 launch)
  k_pre<<<SCAN_NB + 2, 256, 0, stream>>>(count, Wr, a, rel, s_rel);

  // fused: layer-0 gemm (blocks 0..1023, f32 in) + edge histogram (1 edge/thread)
  k_histgemm<<<GEMM_NB + EBLK, 256, 0, stream>>>(dst, count, pl, node, B, W, a,
                                                 s_src, s_dst);

  // CSR scan (row_ptr inlined downstream; scan3 eliminated)
  k_scan1<<<SCAN_NB, 256, 0, stream>>>(count, lscan, bsum);
  k_scan2<<<1, 1024, 0, stream>>>(bsum);
  k_build<<<EBLK, 256, 0, stream>>>(src, dst, et, pl, lscan, bsum, cse);

  // layer 0 aggregate: x1 -> XN
  k_agg<<<2048, 256, 0, stream>>>(lscan, bsum, cse, s_src, s_dst, s_rel, B, XN,
                                  node, XN, out, 0);

  // layer 1: XN(x1) -> xt2 in B (keeps x1); fused finale writes out
  k_gemm1<<<1024, 256, 0, stream>>>(XN, B, W + DIM*DIM, a + 3*DIM, s_src, s_dst);
  k_agg<<<2048, 256, 0, stream>>>(lscan, bsum, cse, s_src, s_dst, s_rel + NREL, B,
                                  nullptr, node, XN, out, 1);
}